// Round 14
// baseline (155.240 us; speedup 1.0000x reference)
//
#include <hip/hip_runtime.h>
#include <hip/hip_bf16.h>

#define N_PTS 20000
#define KNN 16
#define C 256
#define G 16
#define EPS 1e-5f
#define NP 16

typedef __attribute__((ext_vector_type(8))) short short8;
typedef __attribute__((ext_vector_type(4))) short short4b;
typedef __attribute__((ext_vector_type(4))) float f32x4;

__device__ inline unsigned short f2bf(float f) {
    __hip_bfloat16 h = __float2bfloat16(f);   // native RNE cvt on gfx950
    unsigned short u;
    __builtin_memcpy(&u, &h, 2);
    return u;
}
__device__ inline float bf2f(unsigned int u) {
    return __uint_as_float((u & 0xffffu) << 16);
}
__device__ inline short f2bfs(float f) { return (short)f2bf(f); }

// ---------------- K0: w2w1[d][g] = Wp2@Ww1; c1 = bp2@Ww1 + bw1; Wp2bfT[c][d] = bf16(Wp2[d][c])
__global__ __launch_bounds__(256) void k_prep(const float* Wp2, const float* bp2,
                                              const float* Ww1, const float* bw1,
                                              float* w2w1, float* c1,
                                              unsigned short* wp2bft) {
    __shared__ float red[256][17];
    int t = threadIdx.x, b = blockIdx.x;
    float src = (b < C) ? Wp2[b * C + t] : bp2[t];
    #pragma unroll
    for (int g = 0; g < G; ++g) red[t][g] = src * Ww1[t * G + g];
    __syncthreads();
    for (int s = 128; s > 0; s >>= 1) {
        if (t < s) {
            #pragma unroll
            for (int g = 0; g < G; ++g) red[t][g] += red[t + s][g];
        }
        __syncthreads();
    }
    if (t < G) {
        if (b < C) w2w1[b * G + t] = red[0][t];
        else       c1[t] = red[0][t] + bw1[t];
    }
    if (b < C) wp2bft[t * C + b] = f2bf(Wp2[b * C + t]);
}

// ---------------- K1: q/k/v = feat @ W via bf16 MFMA (+bias, +BN+ReLU for q,k); all outputs bf16
// (round-11 structure: BM=128, BN=256, grid 157x3, 8 waves 2Mx4N)
__global__ __launch_bounds__(512, 2) void k_qkv(
    const float* __restrict__ feat,
    const float* __restrict__ Wq, const float* __restrict__ bq, const float* __restrict__ bnq,
    const float* __restrict__ Wk, const float* __restrict__ bk, const float* __restrict__ bnk,
    const float* __restrict__ Wv, const float* __restrict__ bv,
    unsigned short* __restrict__ q_out, unsigned short* __restrict__ k_out,
    unsigned short* __restrict__ v_out) {
    __shared__ __align__(16) unsigned short Asl[128][40];   // [m][k] bf16, pad 8
    __shared__ __align__(16) unsigned short Bsl[256][40];   // [n][k] bf16, pad 8

    const int t = threadIdx.x;
    const int m0 = blockIdx.x * 128;
    const int z = blockIdx.z;
    const float* W    = (z == 0) ? Wq : (z == 1) ? Wk : Wv;
    const float* bias = (z == 0) ? bq : (z == 1) ? bk : bv;
    const float* bn   = (z == 0) ? bnq : bnk;

    const int wv = t >> 6, lane = t & 63, h = lane >> 4, ln = lane & 15;
    const int wm = wv >> 2, wn = wv & 3;

    f32x4 acc[4][4];
    #pragma unroll
    for (int i = 0; i < 4; ++i)
        #pragma unroll
        for (int j = 0; j < 4; ++j) acc[i][j] = (f32x4){0.f, 0.f, 0.f, 0.f};

    const int ar = t >> 3, ak = (t & 7) * 4;
    const int bk_n = (t & 63) * 4, bk_k = t >> 6;

    for (int kb = 0; kb < C; kb += 32) {
        #pragma unroll
        for (int ps = 0; ps < 2; ++ps) {
            int r = ar + 64 * ps;
            int gm = m0 + r; if (gm > N_PTS - 1) gm = N_PTS - 1;
            float4 f = *(const float4*)&feat[gm * C + kb + ak];
            unsigned int u0 = f2bf(f.x) | ((unsigned int)f2bf(f.y) << 16);
            unsigned int u1 = f2bf(f.z) | ((unsigned int)f2bf(f.w) << 16);
            *(uint2*)&Asl[r][ak] = make_uint2(u0, u1);
        }
        #pragma unroll
        for (int ps = 0; ps < 4; ++ps) {
            int kk = bk_k + 8 * ps;
            float4 w = *(const float4*)&W[(kb + kk) * C + bk_n];
            Bsl[bk_n + 0][kk] = f2bf(w.x);
            Bsl[bk_n + 1][kk] = f2bf(w.y);
            Bsl[bk_n + 2][kk] = f2bf(w.z);
            Bsl[bk_n + 3][kk] = f2bf(w.w);
        }
        __syncthreads();
        short8 af[4], bf[4];
        #pragma unroll
        for (int mf = 0; mf < 4; ++mf) af[mf] = *(const short8*)&Asl[64 * wm + 16 * mf + ln][8 * h];
        #pragma unroll
        for (int nf = 0; nf < 4; ++nf) bf[nf] = *(const short8*)&Bsl[64 * wn + 16 * nf + ln][8 * h];
        #pragma unroll
        for (int mf = 0; mf < 4; ++mf)
            #pragma unroll
            for (int nf = 0; nf < 4; ++nf)
                acc[mf][nf] = __builtin_amdgcn_mfma_f32_16x16x32_bf16(af[mf], bf[nf], acc[mf][nf], 0, 0, 0);
        __syncthreads();
    }

    unsigned short* dst = (z == 0) ? q_out : (z == 1) ? k_out : v_out;
    float scv[4], shv[4];
    int cidx[4];
    #pragma unroll
    for (int nf = 0; nf < 4; ++nf) {
        int c = 64 * wn + 16 * nf + ln;
        cidx[nf] = c;
        float bi = bias[c];
        if (z < 2) {
            float ga = bn[c], be = bn[C + c], mu = bn[2 * C + c], va = bn[3 * C + c];
            float s = ga * rsqrtf(va + EPS);
            scv[nf] = s; shv[nf] = (bi - mu) * s + be;
        } else { scv[nf] = 1.f; shv[nf] = bi; }
    }
    #pragma unroll
    for (int mf = 0; mf < 4; ++mf) {
        #pragma unroll
        for (int reg = 0; reg < 4; ++reg) {
            int m = m0 + 64 * wm + 16 * mf + 4 * h + reg;
            if (m >= N_PTS) continue;
            #pragma unroll
            for (int nf = 0; nf < 4; ++nf) {
                float x = acc[mf][nf][reg] * scv[nf] + shv[nf];
                if (z < 2) x = fmaxf(x, 0.f);
                dst[m * C + cidx[nf]] = f2bf(x);
            }
        }
    }
}

// ---------------- K2: qw1 = q @ Ww1, kw1 = k @ Ww1  (bf16 inputs)
__global__ __launch_bounds__(256) void k_qkw(const unsigned short* q_ws, const unsigned short* k_ws,
                                             const float* Ww1, float* qw1, float* kw1) {
    __shared__ float tile[16][260];
    __shared__ float wT[G][260];
    int t = threadIdx.x;
    const unsigned short* src = blockIdx.y ? k_ws : q_ws;
    float* dst = blockIdx.y ? kw1 : qw1;
    int r0 = blockIdx.x * 16;
    #pragma unroll
    for (int i = 0; i < 16; ++i) {
        int e = t + 256 * i;
        wT[e & 15][e >> 4] = Ww1[e];
    }
    #pragma unroll
    for (int i = 0; i < 4; ++i) {
        int e4 = t + 256 * i;
        int row = e4 >> 6, col = (e4 & 63) * 4;
        uint2 u = *(const uint2*)&src[(r0 + row) * C + col];
        tile[row][col + 0] = bf2f(u.x);
        tile[row][col + 1] = bf2f(u.x >> 16);
        tile[row][col + 2] = bf2f(u.y);
        tile[row][col + 3] = bf2f(u.y >> 16);
    }
    __syncthreads();
    int r = t >> 4, g = t & 15;
    float acc = 0.f;
    for (int c = 0; c < C; c += 4) {
        float4 a = *(float4*)&tile[r][c];
        float4 w = *(float4*)&wT[g][c];
        acc += a.x * w.x + a.y * w.y + a.z * w.z + a.w * w.w;
    }
    dst[(r0 + r) * G + g] = acc;
}

// ---------------- K3: fused MFMA attention, 16 points / 256 threads / 4 waves
// XCD-aware chunked block swizzle (bijective for 1250 blocks over 8 XCDs):
// neighboring point-chunks co-locate on one XCD's L2 -> kNN v/kw1/coord gathers hit L2.
__global__ __launch_bounds__(256, 2) void k_attn(
    const float* __restrict__ coord, const int* __restrict__ knn,
    const float* __restrict__ Wp1, const float* __restrict__ bp1, const float* __restrict__ bnp,
    const float* __restrict__ bp2,
    const float* __restrict__ Ww2, const float* __restrict__ bw2, const float* __restrict__ bnw,
    const float* __restrict__ w2w1, const float* __restrict__ c1,
    const float* __restrict__ qw1, const float* __restrict__ kw1,
    const unsigned short* __restrict__ vb, const unsigned short* __restrict__ wp2bft,
    float* __restrict__ out)
{
    __shared__ __align__(16) int   safe_s[256];               // 1 KB
    __shared__ __align__(16) float wp1c[256][4];              // 4 KB
    __shared__ __align__(16) unsigned short wt_l[16][16][20]; // 10 KB  [p][g][k], k=16 -> wsum
    __shared__ __align__(16) unsigned short hwbuf[10368];     // 20.25 KB multi-use

    const int t = threadIdx.x;
    // bijective XCD-chunked swizzle: nwg=1250, q=156, r=2
    int wg;
    {
        int b = blockIdx.x;
        int xcd = b & 7, i = b >> 3;
        wg = (xcd < 2 ? xcd * 157 : 2 * 157 + (xcd - 2) * 156) + i;
    }
    const int n0 = wg * NP;
    const int wv = t >> 6, lane = t & 63, h = lane >> 4, ln = lane & 15;
    const short8 z8 = (short8){0, 0, 0, 0, 0, 0, 0, 0};

    float scwv, shwv, bw2v, c1v;
    {
        float ga = bnw[ln], be = bnw[G + ln], mu = bnw[2 * G + ln], va = bnw[3 * G + ln];
        scwv = ga * rsqrtf(va + EPS);
        shwv = be - mu * scwv;
        bw2v = bw2[ln];
        c1v  = c1[ln];
    }

    // ---- stage: w2w1T + Ww2T into hwbuf, wp1c
    #pragma unroll
    for (int i = 0; i < 16; ++i) {
        int e = t + 256 * i;                       // 4096 = 256 d x 16 g
        hwbuf[(e & 15) * 264 + (e >> 4)] = f2bf(w2w1[e]);
    }
    {
        float ga = bnp[t], be = bnp[C + t], mu = bnp[2 * C + t], va = bnp[3 * C + t];
        float s = ga * rsqrtf(va + EPS);
        wp1c[t][0] = Wp1[t] * s;
        wp1c[t][1] = Wp1[C + t] * s;
        wp1c[t][2] = Wp1[2 * C + t] * s;
        wp1c[t][3] = (bp1[t] - mu) * s + be;
        hwbuf[4224 + (t & 15) * 16 + (t >> 4)] = f2bf(Ww2[t]);  // Ww2T[g'][g]
    }
    // ---- per-thread pos/mask/safe (row = t)
    float px0, py0, pz0, mk0; int safe0;
    {
        const int n = n0 + (t >> 4);
        int ii = knn[n * KNN + (t & 15)];
        mk0 = (ii >= 0) ? 1.f : 0.f;
        safe0 = ii < 0 ? 0 : ii;
        safe_s[t] = safe0;
        px0 = (coord[safe0 * 3]     - coord[n * 3])     * mk0;
        py0 = (coord[safe0 * 3 + 1] - coord[n * 3 + 1]) * mk0;
        pz0 = (coord[safe0 * 3 + 2] - coord[n * 3 + 2]) * mk0;
    }
    __syncthreads();

    // ---- per-wave row pos via shfl (rows 64wv..64wv+63 are wave-private)
    float prx[4], pry[4], prz[4];
    #pragma unroll
    for (int q = 0; q < 4; ++q) {
        int src = 16 * q + ln;
        prx[q] = __shfl(px0, src, 64);
        pry[q] = __shfl(py0, src, 64);
        prz[q] = __shfl(pz0, src, 64);
    }

    // ---- phase B: w1acc = H @ w2w1 (MFMA, A in-flight; wpc in 4-reg halves)
    f32x4 accB[4];
    #pragma unroll
    for (int q = 0; q < 4; ++q) accB[q] = (f32x4){0.f, 0.f, 0.f, 0.f};
    for (int ks = 0; ks < 8; ++ks) {
        int d0 = ks * 32 + h * 8;
        short8 afr[4];
        #pragma unroll
        for (int hp = 0; hp < 2; ++hp) {
            float4 wpc[4];
            #pragma unroll
            for (int j = 0; j < 4; ++j) wpc[j] = *(const float4*)&wp1c[d0 + 4 * hp + j][0];
            #pragma unroll
            for (int q = 0; q < 4; ++q) {
                #pragma unroll
                for (int j = 0; j < 4; ++j) {
                    float hh = fmaxf(prx[q] * wpc[j].x + pry[q] * wpc[j].y + prz[q] * wpc[j].z + wpc[j].w, 0.f);
                    afr[q][4 * hp + j] = f2bfs(hh);
                }
            }
        }
        short8 bfr = *(const short8*)&hwbuf[ln * 264 + d0];
        #pragma unroll
        for (int q = 0; q < 4; ++q)
            accB[q] = __builtin_amdgcn_mfma_f32_16x16x32_bf16(afr[q], bfr, accB[q], 0, 0, 0);
    }

    // ---- phase C: BN+ReLU+offs -> w1 (bf16, wave-private LDS transpose) -> MFMA w2 -> softmax -> wt
    #pragma unroll
    for (int q = 0; q < 4; ++q) {
        const int p = 4 * wv + q;
        float mkq[4]; int sfq[4];
        #pragma unroll
        for (int reg = 0; reg < 4; ++reg) {
            int src = 16 * q + 4 * h + reg;
            mkq[reg] = __shfl(mk0, src, 64);
            sfq[reg] = __shfl(safe0, src, 64);
        }
        #pragma unroll
        for (int reg = 0; reg < 4; ++reg) {
            float kv = kw1[sfq[reg] * G + ln];
            float qv = qw1[(n0 + p) * G + ln];
            float x = accB[q][reg] + kv * mkq[reg] - qv + c1v;
            float w1 = fmaxf(scwv * x + shwv, 0.f);
            hwbuf[4480 + wv * 384 + (4 * h + reg) * 24 + ln] = f2bf(w1);  // w1s[k][g]
        }
        short8 a = z8, b = z8;
        if (h < 2) {
            a = *(const short8*)&hwbuf[4480 + wv * 384 + ln * 24 + 8 * h];  // A[k=ln][g=8h+j]
            b = *(const short8*)&hwbuf[4224 + ln * 16 + 8 * h];             // B[g'=ln][g=8h+j]
        }
        f32x4 w2v4 = __builtin_amdgcn_mfma_f32_16x16x32_bf16(
            a, b, (f32x4){bw2v, bw2v, bw2v, bw2v}, 0, 0, 0);
        float w2r[4] = {w2v4[0], w2v4[1], w2v4[2], w2v4[3]};
        // softmax over k = 4h+reg (rows), per g' = ln
        float m = fmaxf(fmaxf(w2r[0], w2r[1]), fmaxf(w2r[2], w2r[3]));
        m = fmaxf(m, __shfl_xor(m, 16, 64));
        m = fmaxf(m, __shfl_xor(m, 32, 64));
        float e4[4], s = 0.f;
        #pragma unroll
        for (int reg = 0; reg < 4; ++reg) { e4[reg] = __expf(w2r[reg] - m); s += e4[reg]; }
        s += __shfl_xor(s, 16, 64);
        s += __shfl_xor(s, 32, 64);
        float inv = 1.f / s;
        float ws4 = 0.f;
        #pragma unroll
        for (int reg = 0; reg < 4; ++reg) {
            float wt = e4[reg] * inv * mkq[reg];
            ws4 += wt;
            wt_l[p][ln][4 * h + reg] = f2bf(wt);
        }
        ws4 += __shfl_xor(ws4, 16, 64);
        ws4 += __shfl_xor(ws4, 32, 64);
        if (h == 0) wt_l[p][ln][16] = f2bf(ws4);
    }

    __syncthreads();   // phase-B/C hwbuf region dead; safe to reuse as Hw2 dbuf

    // ---- chunk-invariant prefetch for (b): pos of rows 16q+4h+j, wt A-fragments (K=16)
    float pbx[4][4], pby[4][4], pbz[4][4];
    #pragma unroll
    for (int q = 0; q < 4; ++q) {
        #pragma unroll
        for (int j = 0; j < 4; ++j) {
            int src = 16 * q + 4 * h + j;
            pbx[q][j] = __shfl(px0, src, 64);
            pby[q][j] = __shfl(py0, src, 64);
            pbz[q][j] = __shfl(pz0, src, 64);
        }
    }
    short4b awt4[4];
    #pragma unroll
    for (int q = 0; q < 4; ++q)
        awt4[q] = *(const short4b*)&wt_l[4 * wv + q][ln][4 * h];

    const int gq = 4 * wv;
    f32x4 cacc[4];
    #pragma unroll
    for (int qq = 0; qq < 4; ++qq) cacc[qq] = (f32x4){0.f, 0.f, 0.f, 0.f};

    // ---- chunk loop: (b) reg-H -> Hw2[buf] ; bar ; (c) peb += Hw2[buf] x Wp2
    for (int ch = 0; ch < 16; ++ch) {
        const int bw = (ch & 1) * 5184;
        // (b): Hw[g][d] = sum_k wt[p][k][g] * H[p*16+k][ch*16+d]; H in registers
        float4 wc = *(const float4*)&wp1c[ch * 16 + ln][0];
        #pragma unroll
        for (int q = 0; q < 4; ++q) {
            int p = 4 * wv + q;
            short4b bfr;
            #pragma unroll
            for (int j = 0; j < 4; ++j) {
                float hh = fmaxf(pbx[q][j] * wc.x + pby[q][j] * wc.y + pbz[q][j] * wc.z + wc.w, 0.f);
                bfr[j] = f2bfs(hh);
            }
            f32x4 hw = __builtin_amdgcn_mfma_f32_16x16x16bf16_1k(
                awt4[q], bfr, (f32x4){0.f, 0.f, 0.f, 0.f}, 0, 0, 0);
            #pragma unroll
            for (int reg = 0; reg < 4; ++reg)
                hwbuf[bw + (4 * h + reg) * 324 + p * 20 + ln] = f2bf(hw[reg]);
        }
        __syncthreads();
        // (c): peb[point][c] += Hw2[g][point][d] * Wp2[d][c], K=16 (this chunk's d)
        const int dc = ch * 16;
        #pragma unroll
        for (int qq = 0; qq < 4; ++qq) {
            int g = gq + qq;
            short4b a = *(const short4b*)&hwbuf[bw + g * 324 + ln * 20 + 4 * h];
            short4b b = *(const short4b*)&wp2bft[(16 * g + ln) * C + dc + 4 * h];
            cacc[qq] = __builtin_amdgcn_mfma_f32_16x16x16bf16_1k(a, b, cacc[qq], 0, 0, 0);
        }
    }

    // ---- peb -> LDS (overlay), then coalesced gather epilogue
    __syncthreads();   // all waves done reading Hw2
    float (*pebs)[256] = (float (*)[256])(void*)hwbuf;
    #pragma unroll
    for (int qq = 0; qq < 4; ++qq) {
        int g = gq + qq;
        #pragma unroll
        for (int reg = 0; reg < 4; ++reg) {
            int p = 4 * h + reg;                  // (c) D row = point
            pebs[p][16 * g + ln] = cacc[qq][reg];
        }
    }
    __syncthreads();

    {   // thread = (point p_e, group g_e) -> 16 consecutive channels
        const int p_e = t >> 4, g_e = t & 15, c0 = g_e * 16;
        float o[16];
        #pragma unroll
        for (int j = 0; j < 16; ++j) o[j] = pebs[p_e][c0 + j];
        {
            float wsumv = bf2f(wt_l[p_e][g_e][16]);
            float4 b0 = *(const float4*)&bp2[c0];
            float4 b1 = *(const float4*)&bp2[c0 + 4];
            float4 b2 = *(const float4*)&bp2[c0 + 8];
            float4 b3 = *(const float4*)&bp2[c0 + 12];
            o[0] += wsumv * b0.x; o[1] += wsumv * b0.y; o[2] += wsumv * b0.z; o[3] += wsumv * b0.w;
            o[4] += wsumv * b1.x; o[5] += wsumv * b1.y; o[6] += wsumv * b1.z; o[7] += wsumv * b1.w;
            o[8] += wsumv * b2.x; o[9] += wsumv * b2.y; o[10] += wsumv * b2.z; o[11] += wsumv * b2.w;
            o[12] += wsumv * b3.x; o[13] += wsumv * b3.y; o[14] += wsumv * b3.z; o[15] += wsumv * b3.w;
        }
        #pragma unroll
        for (int k = 0; k < KNN; ++k) {
            int sf = safe_s[p_e * 16 + k];
            float w = bf2f(wt_l[p_e][g_e][k]);
            uint4 va = *(const uint4*)&vb[sf * C + c0];
            uint4 vc = *(const uint4*)&vb[sf * C + c0 + 8];
            o[0]  += w * bf2f(va.x); o[1]  += w * bf2f(va.x >> 16);
            o[2]  += w * bf2f(va.y); o[3]  += w * bf2f(va.y >> 16);
            o[4]  += w * bf2f(va.z); o[5]  += w * bf2f(va.z >> 16);
            o[6]  += w * bf2f(va.w); o[7]  += w * bf2f(va.w >> 16);
            o[8]  += w * bf2f(vc.x); o[9]  += w * bf2f(vc.x >> 16);
            o[10] += w * bf2f(vc.y); o[11] += w * bf2f(vc.y >> 16);
            o[12] += w * bf2f(vc.z); o[13] += w * bf2f(vc.z >> 16);
            o[14] += w * bf2f(vc.w); o[15] += w * bf2f(vc.w >> 16);
        }
        float* op = &out[(n0 + p_e) * C + c0];
        *(float4*)&op[0]  = make_float4(o[0], o[1], o[2], o[3]);
        *(float4*)&op[4]  = make_float4(o[4], o[5], o[6], o[7]);
        *(float4*)&op[8]  = make_float4(o[8], o[9], o[10], o[11]);
        *(float4*)&op[12] = make_float4(o[12], o[13], o[14], o[15]);
    }
}

extern "C" void kernel_launch(void* const* d_in, const int* in_sizes, int n_in,
                              void* d_out, int out_size, void* d_ws, size_t ws_size,
                              hipStream_t stream) {
    const float* feat  = (const float*)d_in[0];
    const float* coord = (const float*)d_in[1];
    const int*   knn   = (const int*)d_in[2];
    const float* Wq  = (const float*)d_in[3];
    const float* bq  = (const float*)d_in[4];
    const float* bnq = (const float*)d_in[5];
    const float* Wk  = (const float*)d_in[6];
    const float* bk  = (const float*)d_in[7];
    const float* bnk = (const float*)d_in[8];
    const float* Wv  = (const float*)d_in[9];
    const float* bv  = (const float*)d_in[10];
    const float* Wp1 = (const float*)d_in[11];
    const float* bp1 = (const float*)d_in[12];
    const float* bnp = (const float*)d_in[13];
    const float* Wp2 = (const float*)d_in[14];
    const float* bp2 = (const float*)d_in[15];
    const float* Ww1 = (const float*)d_in[16];
    const float* bw1 = (const float*)d_in[17];
    const float* bnw = (const float*)d_in[18];
    const float* Ww2 = (const float*)d_in[19];
    const float* bw2 = (const float*)d_in[20];

    float* ws = (float*)d_ws;
    unsigned short* q_ws = (unsigned short*)ws;                  // 5.12M bf16
    unsigned short* k_ws = (unsigned short*)(ws + 2560000);      // 5.12M bf16
    unsigned short* v_ws = (unsigned short*)(ws + 5120000);      // 5.12M bf16
    float* qw1   = ws + 7680000;
    float* kw1   = ws + 8080000;
    float* w2w1  = ws + 8480000;
    float* c1    = ws + 8484096;
    unsigned short* wp2bft = (unsigned short*)(ws + 8500000);    // 65536 bf16
    float* outp  = (float*)d_out;

    hipLaunchKernelGGL(k_prep, dim3(257), dim3(256), 0, stream,
                       Wp2, bp2, Ww1, bw1, w2w1, c1, wp2bft);
    hipLaunchKernelGGL(k_qkv, dim3(157, 1, 3), dim3(512), 0, stream,
                       feat, Wq, bq, bnq, Wk, bk, bnk, Wv, bv, q_ws, k_ws, v_ws);
    hipLaunchKernelGGL(k_qkw, dim3(1250, 2), dim3(256), 0, stream,
                       q_ws, k_ws, Ww1, qw1, kw1);
    hipLaunchKernelGGL(k_attn, dim3(1250), dim3(256), 0, stream,
                       coord, knn, Wp1, bp1, bnp, bp2, Ww2, bw2, bnw,
                       w2w1, c1, qw1, kw1, v_ws, wp2bft, outp);
}

// Round 15
// 145.265 us; speedup vs baseline: 1.0687x; 1.0687x over previous
//
#include <hip/hip_runtime.h>
#include <hip/hip_bf16.h>

#define N_PTS 20000
#define KNN 16
#define C 256
#define G 16
#define EPS 1e-5f
#define NP 16

typedef __attribute__((ext_vector_type(8))) short short8;
typedef __attribute__((ext_vector_type(4))) short short4b;
typedef __attribute__((ext_vector_type(4))) float f32x4;

__device__ inline unsigned short f2bf(float f) {
    __hip_bfloat16 h = __float2bfloat16(f);   // native RNE cvt on gfx950
    unsigned short u;
    __builtin_memcpy(&u, &h, 2);
    return u;
}
__device__ inline float bf2f(unsigned int u) {
    return __uint_as_float((u & 0xffffu) << 16);
}
__device__ inline short f2bfs(float f) { return (short)f2bf(f); }

// ---------------- K0: w2w1[d][g] = Wp2@Ww1; c1 = bp2@Ww1 + bw1; Wp2bfT[c][d] = bf16(Wp2[d][c])
__global__ __launch_bounds__(256) void k_prep(const float* Wp2, const float* bp2,
                                              const float* Ww1, const float* bw1,
                                              float* w2w1, float* c1,
                                              unsigned short* wp2bft) {
    __shared__ float red[256][17];
    int t = threadIdx.x, b = blockIdx.x;
    float src = (b < C) ? Wp2[b * C + t] : bp2[t];
    #pragma unroll
    for (int g = 0; g < G; ++g) red[t][g] = src * Ww1[t * G + g];
    __syncthreads();
    for (int s = 128; s > 0; s >>= 1) {
        if (t < s) {
            #pragma unroll
            for (int g = 0; g < G; ++g) red[t][g] += red[t + s][g];
        }
        __syncthreads();
    }
    if (t < G) {
        if (b < C) w2w1[b * G + t] = red[0][t];
        else       c1[t] = red[0][t] + bw1[t];
    }
    if (b < C) wp2bft[t * C + b] = f2bf(Wp2[b * C + t]);
}

// ---------------- K1: q/k/v = feat @ W via bf16 MFMA (+bias, +BN+ReLU for q,k); all outputs bf16
__global__ __launch_bounds__(512, 2) void k_qkv(
    const float* __restrict__ feat,
    const float* __restrict__ Wq, const float* __restrict__ bq, const float* __restrict__ bnq,
    const float* __restrict__ Wk, const float* __restrict__ bk, const float* __restrict__ bnk,
    const float* __restrict__ Wv, const float* __restrict__ bv,
    unsigned short* __restrict__ q_out, unsigned short* __restrict__ k_out,
    unsigned short* __restrict__ v_out) {
    __shared__ __align__(16) unsigned short Asl[128][40];   // [m][k] bf16, pad 8
    __shared__ __align__(16) unsigned short Bsl[256][40];   // [n][k] bf16, pad 8

    const int t = threadIdx.x;
    const int m0 = blockIdx.x * 128;
    const int z = blockIdx.z;
    const float* W    = (z == 0) ? Wq : (z == 1) ? Wk : Wv;
    const float* bias = (z == 0) ? bq : (z == 1) ? bk : bv;
    const float* bn   = (z == 0) ? bnq : bnk;

    const int wv = t >> 6, lane = t & 63, h = lane >> 4, ln = lane & 15;
    const int wm = wv >> 2, wn = wv & 3;

    f32x4 acc[4][4];
    #pragma unroll
    for (int i = 0; i < 4; ++i)
        #pragma unroll
        for (int j = 0; j < 4; ++j) acc[i][j] = (f32x4){0.f, 0.f, 0.f, 0.f};

    const int ar = t >> 3, ak = (t & 7) * 4;
    const int bk_n = (t & 63) * 4, bk_k = t >> 6;

    for (int kb = 0; kb < C; kb += 32) {
        #pragma unroll
        for (int ps = 0; ps < 2; ++ps) {
            int r = ar + 64 * ps;
            int gm = m0 + r; if (gm > N_PTS - 1) gm = N_PTS - 1;
            float4 f = *(const float4*)&feat[gm * C + kb + ak];
            unsigned int u0 = f2bf(f.x) | ((unsigned int)f2bf(f.y) << 16);
            unsigned int u1 = f2bf(f.z) | ((unsigned int)f2bf(f.w) << 16);
            *(uint2*)&Asl[r][ak] = make_uint2(u0, u1);
        }
        #pragma unroll
        for (int ps = 0; ps < 4; ++ps) {
            int kk = bk_k + 8 * ps;
            float4 w = *(const float4*)&W[(kb + kk) * C + bk_n];
            Bsl[bk_n + 0][kk] = f2bf(w.x);
            Bsl[bk_n + 1][kk] = f2bf(w.y);
            Bsl[bk_n + 2][kk] = f2bf(w.z);
            Bsl[bk_n + 3][kk] = f2bf(w.w);
        }
        __syncthreads();
        short8 af[4], bf[4];
        #pragma unroll
        for (int mf = 0; mf < 4; ++mf) af[mf] = *(const short8*)&Asl[64 * wm + 16 * mf + ln][8 * h];
        #pragma unroll
        for (int nf = 0; nf < 4; ++nf) bf[nf] = *(const short8*)&Bsl[64 * wn + 16 * nf + ln][8 * h];
        #pragma unroll
        for (int mf = 0; mf < 4; ++mf)
            #pragma unroll
            for (int nf = 0; nf < 4; ++nf)
                acc[mf][nf] = __builtin_amdgcn_mfma_f32_16x16x32_bf16(af[mf], bf[nf], acc[mf][nf], 0, 0, 0);
        __syncthreads();
    }

    unsigned short* dst = (z == 0) ? q_out : (z == 1) ? k_out : v_out;
    float scv[4], shv[4];
    int cidx[4];
    #pragma unroll
    for (int nf = 0; nf < 4; ++nf) {
        int c = 64 * wn + 16 * nf + ln;
        cidx[nf] = c;
        float bi = bias[c];
        if (z < 2) {
            float ga = bn[c], be = bn[C + c], mu = bn[2 * C + c], va = bn[3 * C + c];
            float s = ga * rsqrtf(va + EPS);
            scv[nf] = s; shv[nf] = (bi - mu) * s + be;
        } else { scv[nf] = 1.f; shv[nf] = bi; }
    }
    #pragma unroll
    for (int mf = 0; mf < 4; ++mf) {
        #pragma unroll
        for (int reg = 0; reg < 4; ++reg) {
            int m = m0 + 64 * wm + 16 * mf + 4 * h + reg;
            if (m >= N_PTS) continue;
            #pragma unroll
            for (int nf = 0; nf < 4; ++nf) {
                float x = acc[mf][nf][reg] * scv[nf] + shv[nf];
                if (z < 2) x = fmaxf(x, 0.f);
                dst[m * C + cidx[nf]] = f2bf(x);
            }
        }
    }
}

// ---------------- K2: qw1 = q @ Ww1, kw1 = k @ Ww1  (bf16 inputs)
__global__ __launch_bounds__(256) void k_qkw(const unsigned short* q_ws, const unsigned short* k_ws,
                                             const float* Ww1, float* qw1, float* kw1) {
    __shared__ float tile[16][260];
    __shared__ float wT[G][260];
    int t = threadIdx.x;
    const unsigned short* src = blockIdx.y ? k_ws : q_ws;
    float* dst = blockIdx.y ? kw1 : qw1;
    int r0 = blockIdx.x * 16;
    #pragma unroll
    for (int i = 0; i < 16; ++i) {
        int e = t + 256 * i;
        wT[e & 15][e >> 4] = Ww1[e];
    }
    #pragma unroll
    for (int i = 0; i < 4; ++i) {
        int e4 = t + 256 * i;
        int row = e4 >> 6, col = (e4 & 63) * 4;
        uint2 u = *(const uint2*)&src[(r0 + row) * C + col];
        tile[row][col + 0] = bf2f(u.x);
        tile[row][col + 1] = bf2f(u.x >> 16);
        tile[row][col + 2] = bf2f(u.y);
        tile[row][col + 3] = bf2f(u.y >> 16);
    }
    __syncthreads();
    int r = t >> 4, g = t & 15;
    float acc = 0.f;
    for (int c = 0; c < C; c += 4) {
        float4 a = *(float4*)&tile[r][c];
        float4 w = *(float4*)&wT[g][c];
        acc += a.x * w.x + a.y * w.y + a.z * w.z + a.w * w.w;
    }
    dst[(r0 + r) * G + g] = acc;
}

// ---------------- K3: fused MFMA attention, 16 points / 256 threads / 4 waves
// v-gather interleaved into chunk loop (k=ch per chunk): loads issued before (b),
// accumulated after (c) -> HBM latency hides under MFMA+barrier slack.
__global__ __launch_bounds__(256, 2) void k_attn(
    const float* __restrict__ coord, const int* __restrict__ knn,
    const float* __restrict__ Wp1, const float* __restrict__ bp1, const float* __restrict__ bnp,
    const float* __restrict__ bp2,
    const float* __restrict__ Ww2, const float* __restrict__ bw2, const float* __restrict__ bnw,
    const float* __restrict__ w2w1, const float* __restrict__ c1,
    const float* __restrict__ qw1, const float* __restrict__ kw1,
    const unsigned short* __restrict__ vb, const unsigned short* __restrict__ wp2bft,
    float* __restrict__ out)
{
    __shared__ __align__(16) int   safe_s[256];               // 1 KB
    __shared__ __align__(16) float wp1c[256][4];              // 4 KB
    __shared__ __align__(16) unsigned short wt_l[16][16][20]; // 10 KB  [p][g][k], k=16 -> wsum
    __shared__ __align__(16) unsigned short hwbuf[10368];     // 20.25 KB multi-use

    const int t = threadIdx.x;
    const int n0 = blockIdx.x * NP;
    const int wv = t >> 6, lane = t & 63, h = lane >> 4, ln = lane & 15;
    const short8 z8 = (short8){0, 0, 0, 0, 0, 0, 0, 0};

    float scwv, shwv, bw2v, c1v;
    {
        float ga = bnw[ln], be = bnw[G + ln], mu = bnw[2 * G + ln], va = bnw[3 * G + ln];
        scwv = ga * rsqrtf(va + EPS);
        shwv = be - mu * scwv;
        bw2v = bw2[ln];
        c1v  = c1[ln];
    }

    // ---- stage: w2w1T + Ww2T into hwbuf, wp1c
    #pragma unroll
    for (int i = 0; i < 16; ++i) {
        int e = t + 256 * i;                       // 4096 = 256 d x 16 g
        hwbuf[(e & 15) * 264 + (e >> 4)] = f2bf(w2w1[e]);
    }
    {
        float ga = bnp[t], be = bnp[C + t], mu = bnp[2 * C + t], va = bnp[3 * C + t];
        float s = ga * rsqrtf(va + EPS);
        wp1c[t][0] = Wp1[t] * s;
        wp1c[t][1] = Wp1[C + t] * s;
        wp1c[t][2] = Wp1[2 * C + t] * s;
        wp1c[t][3] = (bp1[t] - mu) * s + be;
        hwbuf[4224 + (t & 15) * 16 + (t >> 4)] = f2bf(Ww2[t]);  // Ww2T[g'][g]
    }
    // ---- per-thread pos/mask/safe (row = t)
    float px0, py0, pz0, mk0; int safe0;
    {
        const int n = n0 + (t >> 4);
        int ii = knn[n * KNN + (t & 15)];
        mk0 = (ii >= 0) ? 1.f : 0.f;
        safe0 = ii < 0 ? 0 : ii;
        safe_s[t] = safe0;
        px0 = (coord[safe0 * 3]     - coord[n * 3])     * mk0;
        py0 = (coord[safe0 * 3 + 1] - coord[n * 3 + 1]) * mk0;
        pz0 = (coord[safe0 * 3 + 2] - coord[n * 3 + 2]) * mk0;
    }
    __syncthreads();

    // ---- per-wave row pos via shfl (rows 64wv..64wv+63 are wave-private)
    float prx[4], pry[4], prz[4];
    #pragma unroll
    for (int q = 0; q < 4; ++q) {
        int src = 16 * q + ln;
        prx[q] = __shfl(px0, src, 64);
        pry[q] = __shfl(py0, src, 64);
        prz[q] = __shfl(pz0, src, 64);
    }

    // ---- phase B: w1acc = H @ w2w1 (MFMA, A in-flight; wpc in 4-reg halves)
    f32x4 accB[4];
    #pragma unroll
    for (int q = 0; q < 4; ++q) accB[q] = (f32x4){0.f, 0.f, 0.f, 0.f};
    for (int ks = 0; ks < 8; ++ks) {
        int d0 = ks * 32 + h * 8;
        short8 afr[4];
        #pragma unroll
        for (int hp = 0; hp < 2; ++hp) {
            float4 wpc[4];
            #pragma unroll
            for (int j = 0; j < 4; ++j) wpc[j] = *(const float4*)&wp1c[d0 + 4 * hp + j][0];
            #pragma unroll
            for (int q = 0; q < 4; ++q) {
                #pragma unroll
                for (int j = 0; j < 4; ++j) {
                    float hh = fmaxf(prx[q] * wpc[j].x + pry[q] * wpc[j].y + prz[q] * wpc[j].z + wpc[j].w, 0.f);
                    afr[q][4 * hp + j] = f2bfs(hh);
                }
            }
        }
        short8 bfr = *(const short8*)&hwbuf[ln * 264 + d0];
        #pragma unroll
        for (int q = 0; q < 4; ++q)
            accB[q] = __builtin_amdgcn_mfma_f32_16x16x32_bf16(afr[q], bfr, accB[q], 0, 0, 0);
    }

    // ---- phase C: BN+ReLU+offs -> w1 (bf16, wave-private LDS transpose) -> MFMA w2 -> softmax -> wt
    #pragma unroll
    for (int q = 0; q < 4; ++q) {
        const int p = 4 * wv + q;
        float mkq[4]; int sfq[4];
        #pragma unroll
        for (int reg = 0; reg < 4; ++reg) {
            int src = 16 * q + 4 * h + reg;
            mkq[reg] = __shfl(mk0, src, 64);
            sfq[reg] = __shfl(safe0, src, 64);
        }
        #pragma unroll
        for (int reg = 0; reg < 4; ++reg) {
            float kv = kw1[sfq[reg] * G + ln];
            float qv = qw1[(n0 + p) * G + ln];
            float x = accB[q][reg] + kv * mkq[reg] - qv + c1v;
            float w1 = fmaxf(scwv * x + shwv, 0.f);
            hwbuf[4480 + wv * 384 + (4 * h + reg) * 24 + ln] = f2bf(w1);  // w1s[k][g]
        }
        short8 a = z8, b = z8;
        if (h < 2) {
            a = *(const short8*)&hwbuf[4480 + wv * 384 + ln * 24 + 8 * h];  // A[k=ln][g=8h+j]
            b = *(const short8*)&hwbuf[4224 + ln * 16 + 8 * h];             // B[g'=ln][g=8h+j]
        }
        f32x4 w2v4 = __builtin_amdgcn_mfma_f32_16x16x32_bf16(
            a, b, (f32x4){bw2v, bw2v, bw2v, bw2v}, 0, 0, 0);
        float w2r[4] = {w2v4[0], w2v4[1], w2v4[2], w2v4[3]};
        // softmax over k = 4h+reg (rows), per g' = ln
        float m = fmaxf(fmaxf(w2r[0], w2r[1]), fmaxf(w2r[2], w2r[3]));
        m = fmaxf(m, __shfl_xor(m, 16, 64));
        m = fmaxf(m, __shfl_xor(m, 32, 64));
        float e4[4], s = 0.f;
        #pragma unroll
        for (int reg = 0; reg < 4; ++reg) { e4[reg] = __expf(w2r[reg] - m); s += e4[reg]; }
        s += __shfl_xor(s, 16, 64);
        s += __shfl_xor(s, 32, 64);
        float inv = 1.f / s;
        float ws4 = 0.f;
        #pragma unroll
        for (int reg = 0; reg < 4; ++reg) {
            float wt = e4[reg] * inv * mkq[reg];
            ws4 += wt;
            wt_l[p][ln][4 * h + reg] = f2bf(wt);
        }
        ws4 += __shfl_xor(ws4, 16, 64);
        ws4 += __shfl_xor(ws4, 32, 64);
        if (h == 0) wt_l[p][ln][16] = f2bf(ws4);
    }

    __syncthreads();   // phase-B/C hwbuf region dead; safe to reuse as Hw2 dbuf

    // ---- chunk-invariant prefetch for (b): pos of rows 16q+4h+j, wt A-fragments (K=16)
    float pbx[4][4], pby[4][4], pbz[4][4];
    #pragma unroll
    for (int q = 0; q < 4; ++q) {
        #pragma unroll
        for (int j = 0; j < 4; ++j) {
            int src = 16 * q + 4 * h + j;
            pbx[q][j] = __shfl(px0, src, 64);
            pby[q][j] = __shfl(py0, src, 64);
            pbz[q][j] = __shfl(pz0, src, 64);
        }
    }
    short4b awt4[4];
    #pragma unroll
    for (int q = 0; q < 4; ++q)
        awt4[q] = *(const short4b*)&wt_l[4 * wv + q][ln][4 * h];

    const int gq = 4 * wv;
    f32x4 cacc[4];
    #pragma unroll
    for (int qq = 0; qq < 4; ++qq) cacc[qq] = (f32x4){0.f, 0.f, 0.f, 0.f};

    // v-gather interleave state (epilogue mapping)
    const int p_e = t >> 4, g_e = t & 15, c0 = g_e * 16;
    float ov[16];
    #pragma unroll
    for (int j = 0; j < 16; ++j) ov[j] = 0.f;

    // ---- chunk loop: issue v-load(k=ch) ; (b) reg-H -> Hw2[buf] ; bar ; (c) ; v-accum
    for (int ch = 0; ch < 16; ++ch) {
        const int bw = (ch & 1) * 5184;
        // issue v-gather loads for neighbor k=ch (latency hides under (b)+bar+(c))
        const int sf_v = safe_s[p_e * 16 + ch];
        uint4 va = *(const uint4*)&vb[sf_v * C + c0];
        uint4 vc = *(const uint4*)&vb[sf_v * C + c0 + 8];
        // (b): Hw[g][d] = sum_k wt[p][k][g] * H[p*16+k][ch*16+d]; H in registers
        float4 wc = *(const float4*)&wp1c[ch * 16 + ln][0];
        #pragma unroll
        for (int q = 0; q < 4; ++q) {
            int p = 4 * wv + q;
            short4b bfr;
            #pragma unroll
            for (int j = 0; j < 4; ++j) {
                float hh = fmaxf(pbx[q][j] * wc.x + pby[q][j] * wc.y + pbz[q][j] * wc.z + wc.w, 0.f);
                bfr[j] = f2bfs(hh);
            }
            f32x4 hw = __builtin_amdgcn_mfma_f32_16x16x16bf16_1k(
                awt4[q], bfr, (f32x4){0.f, 0.f, 0.f, 0.f}, 0, 0, 0);
            #pragma unroll
            for (int reg = 0; reg < 4; ++reg)
                hwbuf[bw + (4 * h + reg) * 324 + p * 20 + ln] = f2bf(hw[reg]);
        }
        __syncthreads();
        // (c): peb[point][c] += Hw2[g][point][d] * Wp2[d][c], K=16 (this chunk's d)
        const int dc = ch * 16;
        #pragma unroll
        for (int qq = 0; qq < 4; ++qq) {
            int g = gq + qq;
            short4b a = *(const short4b*)&hwbuf[bw + g * 324 + ln * 20 + 4 * h];
            short4b b = *(const short4b*)&wp2bft[(16 * g + ln) * C + dc + 4 * h];
            cacc[qq] = __builtin_amdgcn_mfma_f32_16x16x16bf16_1k(a, b, cacc[qq], 0, 0, 0);
        }
        // v-accum for neighbor k=ch
        {
            float w = bf2f(wt_l[p_e][g_e][ch]);
            ov[0]  += w * bf2f(va.x); ov[1]  += w * bf2f(va.x >> 16);
            ov[2]  += w * bf2f(va.y); ov[3]  += w * bf2f(va.y >> 16);
            ov[4]  += w * bf2f(va.z); ov[5]  += w * bf2f(va.z >> 16);
            ov[6]  += w * bf2f(va.w); ov[7]  += w * bf2f(va.w >> 16);
            ov[8]  += w * bf2f(vc.x); ov[9]  += w * bf2f(vc.x >> 16);
            ov[10] += w * bf2f(vc.y); ov[11] += w * bf2f(vc.y >> 16);
            ov[12] += w * bf2f(vc.z); ov[13] += w * bf2f(vc.z >> 16);
            ov[14] += w * bf2f(vc.w); ov[15] += w * bf2f(vc.w >> 16);
        }
    }

    // ---- peb -> LDS (overlay), then register-only epilogue
    __syncthreads();   // all waves done reading Hw2
    float (*pebs)[256] = (float (*)[256])(void*)hwbuf;
    #pragma unroll
    for (int qq = 0; qq < 4; ++qq) {
        int g = gq + qq;
        #pragma unroll
        for (int reg = 0; reg < 4; ++reg) {
            int p = 4 * h + reg;                  // (c) D row = point
            pebs[p][16 * g + ln] = cacc[qq][reg];
        }
    }
    __syncthreads();

    {   // thread = (point p_e, group g_e) -> 16 consecutive channels
        float o[16];
        #pragma unroll
        for (int j = 0; j < 16; ++j) o[j] = pebs[p_e][c0 + j] + ov[j];
        {
            float wsumv = bf2f(wt_l[p_e][g_e][16]);
            float4 b0 = *(const float4*)&bp2[c0];
            float4 b1 = *(const float4*)&bp2[c0 + 4];
            float4 b2 = *(const float4*)&bp2[c0 + 8];
            float4 b3 = *(const float4*)&bp2[c0 + 12];
            o[0] += wsumv * b0.x; o[1] += wsumv * b0.y; o[2] += wsumv * b0.z; o[3] += wsumv * b0.w;
            o[4] += wsumv * b1.x; o[5] += wsumv * b1.y; o[6] += wsumv * b1.z; o[7] += wsumv * b1.w;
            o[8] += wsumv * b2.x; o[9] += wsumv * b2.y; o[10] += wsumv * b2.z; o[11] += wsumv * b2.w;
            o[12] += wsumv * b3.x; o[13] += wsumv * b3.y; o[14] += wsumv * b3.z; o[15] += wsumv * b3.w;
        }
        float* op = &out[(n0 + p_e) * C + c0];
        *(float4*)&op[0]  = make_float4(o[0], o[1], o[2], o[3]);
        *(float4*)&op[4]  = make_float4(o[4], o[5], o[6], o[7]);
        *(float4*)&op[8]  = make_float4(o[8], o[9], o[10], o[11]);
        *(float4*)&op[12] = make_float4(o[12], o[13], o[14], o[15]);
    }
}

extern "C" void kernel_launch(void* const* d_in, const int* in_sizes, int n_in,
                              void* d_out, int out_size, void* d_ws, size_t ws_size,
                              hipStream_t stream) {
    const float* feat  = (const float*)d_in[0];
    const float* coord = (const float*)d_in[1];
    const int*   knn   = (const int*)d_in[2];
    const float* Wq  = (const float*)d_in[3];
    const float* bq  = (const float*)d_in[4];
    const float* bnq = (const float*)d_in[5];
    const float* Wk  = (const float*)d_in[6];
    const float* bk  = (const float*)d_in[7];
    const float* bnk = (const float*)d_in[8];
    const float* Wv  = (const float*)d_in[9];
    const float* bv  = (const float*)d_in[10];
    const float* Wp1 = (const float*)d_in[11];
    const float* bp1 = (const float*)d_in[12];
    const float* bnp = (const float*)d_in[13];
    const float* Wp2 = (const float*)d_in[14];
    const float* bp2 = (const float*)d_in[15];
    const float* Ww1 = (const float*)d_in[16];
    const float* bw1 = (const float*)d_in[17];
    const float* bnw = (const float*)d_in[18];
    const float* Ww2 = (const float*)d_in[19];
    const float* bw2 = (const float*)d_in[20];

    float* ws = (float*)d_ws;
    unsigned short* q_ws = (unsigned short*)ws;                  // 5.12M bf16
    unsigned short* k_ws = (unsigned short*)(ws + 2560000);      // 5.12M bf16
    unsigned short* v_ws = (unsigned short*)(ws + 5120000);      // 5.12M bf16
    float* qw1   = ws + 7680000;
    float* kw1   = ws + 8080000;
    float* w2w1  = ws + 8480000;
    float* c1    = ws + 8484096;
    unsigned short* wp2bft = (unsigned short*)(ws + 8500000);    // 65536 bf16
    float* outp  = (float*)d_out;

    hipLaunchKernelGGL(k_prep, dim3(257), dim3(256), 0, stream,
                       Wp2, bp2, Ww1, bw1, w2w1, c1, wp2bft);
    hipLaunchKernelGGL(k_qkv, dim3(157, 1, 3), dim3(512), 0, stream,
                       feat, Wq, bq, bnq, Wk, bk, bnk, Wv, bv, q_ws, k_ws, v_ws);
    hipLaunchKernelGGL(k_qkw, dim3(1250, 2), dim3(256), 0, stream,
                       q_ws, k_ws, Ww1, qw1, kw1);
    hipLaunchKernelGGL(k_attn, dim3(1250), dim3(256), 0, stream,
                       coord, knn, Wp1, bp1, bnp, bp2, Ww2, bw2, bnw,
                       w2w1, c1, qw1, kw1, v_ws, wp2bft, outp);
}

// Round 16
// 140.234 us; speedup vs baseline: 1.1070x; 1.0359x over previous
//
#include <hip/hip_runtime.h>
#include <hip/hip_bf16.h>

#define N_PTS 20000
#define KNN 16
#define C 256
#define G 16
#define EPS 1e-5f
#define NP 16

typedef __attribute__((ext_vector_type(8))) short short8;
typedef __attribute__((ext_vector_type(4))) short short4b;
typedef __attribute__((ext_vector_type(4))) float f32x4;

__device__ inline unsigned short f2bf(float f) {
    __hip_bfloat16 h = __float2bfloat16(f);   // native RNE cvt on gfx950
    unsigned short u;
    __builtin_memcpy(&u, &h, 2);
    return u;
}
__device__ inline float bf2f(unsigned int u) {
    return __uint_as_float((u & 0xffffu) << 16);
}
__device__ inline short f2bfs(float f) { return (short)f2bf(f); }

// ---------------- K0: w2w1[d][g] = Wp2@Ww1; c1 = bp2@Ww1 + bw1; Wp2bfT[c][d] = bf16(Wp2[d][c])
__global__ __launch_bounds__(256) void k_prep(const float* Wp2, const float* bp2,
                                              const float* Ww1, const float* bw1,
                                              float* w2w1, float* c1,
                                              unsigned short* wp2bft) {
    __shared__ float red[256][17];
    int t = threadIdx.x, b = blockIdx.x;
    float src = (b < C) ? Wp2[b * C + t] : bp2[t];
    #pragma unroll
    for (int g = 0; g < G; ++g) red[t][g] = src * Ww1[t * G + g];
    __syncthreads();
    for (int s = 128; s > 0; s >>= 1) {
        if (t < s) {
            #pragma unroll
            for (int g = 0; g < G; ++g) red[t][g] += red[t + s][g];
        }
        __syncthreads();
    }
    if (t < G) {
        if (b < C) w2w1[b * G + t] = red[0][t];
        else       c1[t] = red[0][t] + bw1[t];
    }
    if (b < C) wp2bft[t * C + b] = f2bf(Wp2[b * C + t]);
}

// ---------------- K1: q/k/v = feat @ W via bf16 MFMA (+bias, +BN+ReLU for q,k); all outputs bf16
__global__ __launch_bounds__(512, 2) void k_qkv(
    const float* __restrict__ feat,
    const float* __restrict__ Wq, const float* __restrict__ bq, const float* __restrict__ bnq,
    const float* __restrict__ Wk, const float* __restrict__ bk, const float* __restrict__ bnk,
    const float* __restrict__ Wv, const float* __restrict__ bv,
    unsigned short* __restrict__ q_out, unsigned short* __restrict__ k_out,
    unsigned short* __restrict__ v_out) {
    __shared__ __align__(16) unsigned short Asl[128][40];   // [m][k] bf16, pad 8
    __shared__ __align__(16) unsigned short Bsl[256][40];   // [n][k] bf16, pad 8

    const int t = threadIdx.x;
    const int m0 = blockIdx.x * 128;
    const int z = blockIdx.z;
    const float* W    = (z == 0) ? Wq : (z == 1) ? Wk : Wv;
    const float* bias = (z == 0) ? bq : (z == 1) ? bk : bv;
    const float* bn   = (z == 0) ? bnq : bnk;

    const int wv = t >> 6, lane = t & 63, h = lane >> 4, ln = lane & 15;
    const int wm = wv >> 2, wn = wv & 3;

    f32x4 acc[4][4];
    #pragma unroll
    for (int i = 0; i < 4; ++i)
        #pragma unroll
        for (int j = 0; j < 4; ++j) acc[i][j] = (f32x4){0.f, 0.f, 0.f, 0.f};

    const int ar = t >> 3, ak = (t & 7) * 4;
    const int bk_n = (t & 63) * 4, bk_k = t >> 6;

    for (int kb = 0; kb < C; kb += 32) {
        #pragma unroll
        for (int ps = 0; ps < 2; ++ps) {
            int r = ar + 64 * ps;
            int gm = m0 + r; if (gm > N_PTS - 1) gm = N_PTS - 1;
            float4 f = *(const float4*)&feat[gm * C + kb + ak];
            unsigned int u0 = f2bf(f.x) | ((unsigned int)f2bf(f.y) << 16);
            unsigned int u1 = f2bf(f.z) | ((unsigned int)f2bf(f.w) << 16);
            *(uint2*)&Asl[r][ak] = make_uint2(u0, u1);
        }
        #pragma unroll
        for (int ps = 0; ps < 4; ++ps) {
            int kk = bk_k + 8 * ps;
            float4 w = *(const float4*)&W[(kb + kk) * C + bk_n];
            Bsl[bk_n + 0][kk] = f2bf(w.x);
            Bsl[bk_n + 1][kk] = f2bf(w.y);
            Bsl[bk_n + 2][kk] = f2bf(w.z);
            Bsl[bk_n + 3][kk] = f2bf(w.w);
        }
        __syncthreads();
        short8 af[4], bf[4];
        #pragma unroll
        for (int mf = 0; mf < 4; ++mf) af[mf] = *(const short8*)&Asl[64 * wm + 16 * mf + ln][8 * h];
        #pragma unroll
        for (int nf = 0; nf < 4; ++nf) bf[nf] = *(const short8*)&Bsl[64 * wn + 16 * nf + ln][8 * h];
        #pragma unroll
        for (int mf = 0; mf < 4; ++mf)
            #pragma unroll
            for (int nf = 0; nf < 4; ++nf)
                acc[mf][nf] = __builtin_amdgcn_mfma_f32_16x16x32_bf16(af[mf], bf[nf], acc[mf][nf], 0, 0, 0);
        __syncthreads();
    }

    unsigned short* dst = (z == 0) ? q_out : (z == 1) ? k_out : v_out;
    float scv[4], shv[4];
    int cidx[4];
    #pragma unroll
    for (int nf = 0; nf < 4; ++nf) {
        int c = 64 * wn + 16 * nf + ln;
        cidx[nf] = c;
        float bi = bias[c];
        if (z < 2) {
            float ga = bn[c], be = bn[C + c], mu = bn[2 * C + c], va = bn[3 * C + c];
            float s = ga * rsqrtf(va + EPS);
            scv[nf] = s; shv[nf] = (bi - mu) * s + be;
        } else { scv[nf] = 1.f; shv[nf] = bi; }
    }
    #pragma unroll
    for (int mf = 0; mf < 4; ++mf) {
        #pragma unroll
        for (int reg = 0; reg < 4; ++reg) {
            int m = m0 + 64 * wm + 16 * mf + 4 * h + reg;
            if (m >= N_PTS) continue;
            #pragma unroll
            for (int nf = 0; nf < 4; ++nf) {
                float x = acc[mf][nf][reg] * scv[nf] + shv[nf];
                if (z < 2) x = fmaxf(x, 0.f);
                dst[m * C + cidx[nf]] = f2bf(x);
            }
        }
    }
}

// ---------------- K2: qw1 = q @ Ww1, kw1 = k @ Ww1  (bf16 inputs)
__global__ __launch_bounds__(256) void k_qkw(const unsigned short* q_ws, const unsigned short* k_ws,
                                             const float* Ww1, float* qw1, float* kw1) {
    __shared__ float tile[16][260];
    __shared__ float wT[G][260];
    int t = threadIdx.x;
    const unsigned short* src = blockIdx.y ? k_ws : q_ws;
    float* dst = blockIdx.y ? kw1 : qw1;
    int r0 = blockIdx.x * 16;
    #pragma unroll
    for (int i = 0; i < 16; ++i) {
        int e = t + 256 * i;
        wT[e & 15][e >> 4] = Ww1[e];
    }
    #pragma unroll
    for (int i = 0; i < 4; ++i) {
        int e4 = t + 256 * i;
        int row = e4 >> 6, col = (e4 & 63) * 4;
        uint2 u = *(const uint2*)&src[(r0 + row) * C + col];
        tile[row][col + 0] = bf2f(u.x);
        tile[row][col + 1] = bf2f(u.x >> 16);
        tile[row][col + 2] = bf2f(u.y);
        tile[row][col + 3] = bf2f(u.y >> 16);
    }
    __syncthreads();
    int r = t >> 4, g = t & 15;
    float acc = 0.f;
    for (int c = 0; c < C; c += 4) {
        float4 a = *(float4*)&tile[r][c];
        float4 w = *(float4*)&wT[g][c];
        acc += a.x * w.x + a.y * w.y + a.z * w.z + a.w * w.w;
    }
    dst[(r0 + r) * G + g] = acc;
}

// ---------------- K3: fused MFMA attention, 16 points / 256 threads / 4 waves
// (256,3): current reg demand (~76 VGPR, no spill at (256,2)) fits the ~170-reg cap
// -> 3 blocks/CU for latency hiding across the 16-barrier chunk loop.
__global__ __launch_bounds__(256, 3) void k_attn(
    const float* __restrict__ coord, const int* __restrict__ knn,
    const float* __restrict__ Wp1, const float* __restrict__ bp1, const float* __restrict__ bnp,
    const float* __restrict__ bp2,
    const float* __restrict__ Ww2, const float* __restrict__ bw2, const float* __restrict__ bnw,
    const float* __restrict__ w2w1, const float* __restrict__ c1,
    const float* __restrict__ qw1, const float* __restrict__ kw1,
    const unsigned short* __restrict__ vb, const unsigned short* __restrict__ wp2bft,
    float* __restrict__ out)
{
    __shared__ __align__(16) int   safe_s[256];               // 1 KB
    __shared__ __align__(16) float wp1c[256][4];              // 4 KB
    __shared__ __align__(16) unsigned short wt_l[16][16][20]; // 10 KB  [p][g][k], k=16 -> wsum
    __shared__ __align__(16) unsigned short hwbuf[10368];     // 20.25 KB multi-use

    const int t = threadIdx.x;
    const int n0 = blockIdx.x * NP;
    const int wv = t >> 6, lane = t & 63, h = lane >> 4, ln = lane & 15;
    const short8 z8 = (short8){0, 0, 0, 0, 0, 0, 0, 0};

    float scwv, shwv, bw2v, c1v;
    {
        float ga = bnw[ln], be = bnw[G + ln], mu = bnw[2 * G + ln], va = bnw[3 * G + ln];
        scwv = ga * rsqrtf(va + EPS);
        shwv = be - mu * scwv;
        bw2v = bw2[ln];
        c1v  = c1[ln];
    }

    // ---- stage: w2w1T + Ww2T into hwbuf, wp1c
    #pragma unroll
    for (int i = 0; i < 16; ++i) {
        int e = t + 256 * i;                       // 4096 = 256 d x 16 g
        hwbuf[(e & 15) * 264 + (e >> 4)] = f2bf(w2w1[e]);
    }
    {
        float ga = bnp[t], be = bnp[C + t], mu = bnp[2 * C + t], va = bnp[3 * C + t];
        float s = ga * rsqrtf(va + EPS);
        wp1c[t][0] = Wp1[t] * s;
        wp1c[t][1] = Wp1[C + t] * s;
        wp1c[t][2] = Wp1[2 * C + t] * s;
        wp1c[t][3] = (bp1[t] - mu) * s + be;
        hwbuf[4224 + (t & 15) * 16 + (t >> 4)] = f2bf(Ww2[t]);  // Ww2T[g'][g]
    }
    // ---- per-thread pos/mask/safe (row = t)
    float px0, py0, pz0, mk0; int safe0;
    {
        const int n = n0 + (t >> 4);
        int ii = knn[n * KNN + (t & 15)];
        mk0 = (ii >= 0) ? 1.f : 0.f;
        safe0 = ii < 0 ? 0 : ii;
        safe_s[t] = safe0;
        px0 = (coord[safe0 * 3]     - coord[n * 3])     * mk0;
        py0 = (coord[safe0 * 3 + 1] - coord[n * 3 + 1]) * mk0;
        pz0 = (coord[safe0 * 3 + 2] - coord[n * 3 + 2]) * mk0;
    }
    __syncthreads();

    // ---- per-wave row pos via shfl (rows 64wv..64wv+63 are wave-private)
    float prx[4], pry[4], prz[4];
    #pragma unroll
    for (int q = 0; q < 4; ++q) {
        int src = 16 * q + ln;
        prx[q] = __shfl(px0, src, 64);
        pry[q] = __shfl(py0, src, 64);
        prz[q] = __shfl(pz0, src, 64);
    }

    // ---- phase B: w1acc = H @ w2w1 (MFMA, A in-flight; wpc in 4-reg halves)
    f32x4 accB[4];
    #pragma unroll
    for (int q = 0; q < 4; ++q) accB[q] = (f32x4){0.f, 0.f, 0.f, 0.f};
    for (int ks = 0; ks < 8; ++ks) {
        int d0 = ks * 32 + h * 8;
        short8 afr[4];
        #pragma unroll
        for (int hp = 0; hp < 2; ++hp) {
            float4 wpc[4];
            #pragma unroll
            for (int j = 0; j < 4; ++j) wpc[j] = *(const float4*)&wp1c[d0 + 4 * hp + j][0];
            #pragma unroll
            for (int q = 0; q < 4; ++q) {
                #pragma unroll
                for (int j = 0; j < 4; ++j) {
                    float hh = fmaxf(prx[q] * wpc[j].x + pry[q] * wpc[j].y + prz[q] * wpc[j].z + wpc[j].w, 0.f);
                    afr[q][4 * hp + j] = f2bfs(hh);
                }
            }
        }
        short8 bfr = *(const short8*)&hwbuf[ln * 264 + d0];
        #pragma unroll
        for (int q = 0; q < 4; ++q)
            accB[q] = __builtin_amdgcn_mfma_f32_16x16x32_bf16(afr[q], bfr, accB[q], 0, 0, 0);
    }

    // ---- phase C: BN+ReLU+offs -> w1 (bf16, wave-private LDS transpose) -> MFMA w2 -> softmax -> wt
    #pragma unroll
    for (int q = 0; q < 4; ++q) {
        const int p = 4 * wv + q;
        float mkq[4]; int sfq[4];
        #pragma unroll
        for (int reg = 0; reg < 4; ++reg) {
            int src = 16 * q + 4 * h + reg;
            mkq[reg] = __shfl(mk0, src, 64);
            sfq[reg] = __shfl(safe0, src, 64);
        }
        #pragma unroll
        for (int reg = 0; reg < 4; ++reg) {
            float kv = kw1[sfq[reg] * G + ln];
            float qv = qw1[(n0 + p) * G + ln];
            float x = accB[q][reg] + kv * mkq[reg] - qv + c1v;
            float w1 = fmaxf(scwv * x + shwv, 0.f);
            hwbuf[4480 + wv * 384 + (4 * h + reg) * 24 + ln] = f2bf(w1);  // w1s[k][g]
        }
        short8 a = z8, b = z8;
        if (h < 2) {
            a = *(const short8*)&hwbuf[4480 + wv * 384 + ln * 24 + 8 * h];  // A[k=ln][g=8h+j]
            b = *(const short8*)&hwbuf[4224 + ln * 16 + 8 * h];             // B[g'=ln][g=8h+j]
        }
        f32x4 w2v4 = __builtin_amdgcn_mfma_f32_16x16x32_bf16(
            a, b, (f32x4){bw2v, bw2v, bw2v, bw2v}, 0, 0, 0);
        float w2r[4] = {w2v4[0], w2v4[1], w2v4[2], w2v4[3]};
        // softmax over k = 4h+reg (rows), per g' = ln
        float m = fmaxf(fmaxf(w2r[0], w2r[1]), fmaxf(w2r[2], w2r[3]));
        m = fmaxf(m, __shfl_xor(m, 16, 64));
        m = fmaxf(m, __shfl_xor(m, 32, 64));
        float e4[4], s = 0.f;
        #pragma unroll
        for (int reg = 0; reg < 4; ++reg) { e4[reg] = __expf(w2r[reg] - m); s += e4[reg]; }
        s += __shfl_xor(s, 16, 64);
        s += __shfl_xor(s, 32, 64);
        float inv = 1.f / s;
        float ws4 = 0.f;
        #pragma unroll
        for (int reg = 0; reg < 4; ++reg) {
            float wt = e4[reg] * inv * mkq[reg];
            ws4 += wt;
            wt_l[p][ln][4 * h + reg] = f2bf(wt);
        }
        ws4 += __shfl_xor(ws4, 16, 64);
        ws4 += __shfl_xor(ws4, 32, 64);
        if (h == 0) wt_l[p][ln][16] = f2bf(ws4);
    }

    __syncthreads();   // phase-B/C hwbuf region dead; safe to reuse as Hw2 dbuf

    // ---- chunk-invariant prefetch for (b): pos of rows 16q+4h+j, wt A-fragments (K=16)
    float pbx[4][4], pby[4][4], pbz[4][4];
    #pragma unroll
    for (int q = 0; q < 4; ++q) {
        #pragma unroll
        for (int j = 0; j < 4; ++j) {
            int src = 16 * q + 4 * h + j;
            pbx[q][j] = __shfl(px0, src, 64);
            pby[q][j] = __shfl(py0, src, 64);
            pbz[q][j] = __shfl(pz0, src, 64);
        }
    }
    short4b awt4[4];
    #pragma unroll
    for (int q = 0; q < 4; ++q)
        awt4[q] = *(const short4b*)&wt_l[4 * wv + q][ln][4 * h];

    const int gq = 4 * wv;
    f32x4 cacc[4];
    #pragma unroll
    for (int qq = 0; qq < 4; ++qq) cacc[qq] = (f32x4){0.f, 0.f, 0.f, 0.f};

    // v-gather interleave state (epilogue mapping)
    const int p_e = t >> 4, g_e = t & 15, c0 = g_e * 16;
    float ov[16];
    #pragma unroll
    for (int j = 0; j < 16; ++j) ov[j] = 0.f;

    // ---- chunk loop: issue v-load(k=ch) ; (b) reg-H -> Hw2[buf] ; bar ; (c) ; v-accum
    for (int ch = 0; ch < 16; ++ch) {
        const int bw = (ch & 1) * 5184;
        // issue v-gather loads for neighbor k=ch (latency hides under (b)+bar+(c))
        const int sf_v = safe_s[p_e * 16 + ch];
        uint4 va = *(const uint4*)&vb[sf_v * C + c0];
        uint4 vc = *(const uint4*)&vb[sf_v * C + c0 + 8];
        // (b): Hw[g][d] = sum_k wt[p][k][g] * H[p*16+k][ch*16+d]; H in registers
        float4 wc = *(const float4*)&wp1c[ch * 16 + ln][0];
        #pragma unroll
        for (int q = 0; q < 4; ++q) {
            int p = 4 * wv + q;
            short4b bfr;
            #pragma unroll
            for (int j = 0; j < 4; ++j) {
                float hh = fmaxf(pbx[q][j] * wc.x + pby[q][j] * wc.y + pbz[q][j] * wc.z + wc.w, 0.f);
                bfr[j] = f2bfs(hh);
            }
            f32x4 hw = __builtin_amdgcn_mfma_f32_16x16x16bf16_1k(
                awt4[q], bfr, (f32x4){0.f, 0.f, 0.f, 0.f}, 0, 0, 0);
            #pragma unroll
            for (int reg = 0; reg < 4; ++reg)
                hwbuf[bw + (4 * h + reg) * 324 + p * 20 + ln] = f2bf(hw[reg]);
        }
        __syncthreads();
        // (c): peb[point][c] += Hw2[g][point][d] * Wp2[d][c], K=16 (this chunk's d)
        const int dc = ch * 16;
        #pragma unroll
        for (int qq = 0; qq < 4; ++qq) {
            int g = gq + qq;
            short4b a = *(const short4b*)&hwbuf[bw + g * 324 + ln * 20 + 4 * h];
            short4b b = *(const short4b*)&wp2bft[(16 * g + ln) * C + dc + 4 * h];
            cacc[qq] = __builtin_amdgcn_mfma_f32_16x16x16bf16_1k(a, b, cacc[qq], 0, 0, 0);
        }
        // v-accum for neighbor k=ch
        {
            float w = bf2f(wt_l[p_e][g_e][ch]);
            ov[0]  += w * bf2f(va.x); ov[1]  += w * bf2f(va.x >> 16);
            ov[2]  += w * bf2f(va.y); ov[3]  += w * bf2f(va.y >> 16);
            ov[4]  += w * bf2f(va.z); ov[5]  += w * bf2f(va.z >> 16);
            ov[6]  += w * bf2f(va.w); ov[7]  += w * bf2f(va.w >> 16);
            ov[8]  += w * bf2f(vc.x); ov[9]  += w * bf2f(vc.x >> 16);
            ov[10] += w * bf2f(vc.y); ov[11] += w * bf2f(vc.y >> 16);
            ov[12] += w * bf2f(vc.z); ov[13] += w * bf2f(vc.z >> 16);
            ov[14] += w * bf2f(vc.w); ov[15] += w * bf2f(vc.w >> 16);
        }
    }

    // ---- peb -> LDS (overlay), then register-only epilogue
    __syncthreads();   // all waves done reading Hw2
    float (*pebs)[256] = (float (*)[256])(void*)hwbuf;
    #pragma unroll
    for (int qq = 0; qq < 4; ++qq) {
        int g = gq + qq;
        #pragma unroll
        for (int reg = 0; reg < 4; ++reg) {
            int p = 4 * h + reg;                  // (c) D row = point
            pebs[p][16 * g + ln] = cacc[qq][reg];
        }
    }
    __syncthreads();

    {   // thread = (point p_e, group g_e) -> 16 consecutive channels
        float o[16];
        #pragma unroll
        for (int j = 0; j < 16; ++j) o[j] = pebs[p_e][c0 + j] + ov[j];
        {
            float wsumv = bf2f(wt_l[p_e][g_e][16]);
            float4 b0 = *(const float4*)&bp2[c0];
            float4 b1 = *(const float4*)&bp2[c0 + 4];
            float4 b2 = *(const float4*)&bp2[c0 + 8];
            float4 b3 = *(const float4*)&bp2[c0 + 12];
            o[0] += wsumv * b0.x; o[1] += wsumv * b0.y; o[2] += wsumv * b0.z; o[3] += wsumv * b0.w;
            o[4] += wsumv * b1.x; o[5] += wsumv * b1.y; o[6] += wsumv * b1.z; o[7] += wsumv * b1.w;
            o[8] += wsumv * b2.x; o[9] += wsumv * b2.y; o[10] += wsumv * b2.z; o[11] += wsumv * b2.w;
            o[12] += wsumv * b3.x; o[13] += wsumv * b3.y; o[14] += wsumv * b3.z; o[15] += wsumv * b3.w;
        }
        float* op = &out[(n0 + p_e) * C + c0];
        *(float4*)&op[0]  = make_float4(o[0], o[1], o[2], o[3]);
        *(float4*)&op[4]  = make_float4(o[4], o[5], o[6], o[7]);
        *(float4*)&op[8]  = make_float4(o[8], o[9], o[10], o[11]);
        *(float4*)&op[12] = make_float4(o[12], o[13], o[14], o[15]);
    }
}

extern "C" void kernel_launch(void* const* d_in, const int* in_sizes, int n_in,
                              void* d_out, int out_size, void* d_ws, size_t ws_size,
                              hipStream_t stream) {
    const float* feat  = (const float*)d_in[0];
    const float* coord = (const float*)d_in[1];
    const int*   knn   = (const int*)d_in[2];
    const float* Wq  = (const float*)d_in[3];
    const float* bq  = (const float*)d_in[4];
    const float* bnq = (const float*)d_in[5];
    const float* Wk  = (const float*)d_in[6];
    const float* bk  = (const float*)d_in[7];
    const float* bnk = (const float*)d_in[8];
    const float* Wv  = (const float*)d_in[9];
    const float* bv  = (const float*)d_in[10];
    const float* Wp1 = (const float*)d_in[11];
    const float* bp1 = (const float*)d_in[12];
    const float* bnp = (const float*)d_in[13];
    const float* Wp2 = (const float*)d_in[14];
    const float* bp2 = (const float*)d_in[15];
    const float* Ww1 = (const float*)d_in[16];
    const float* bw1 = (const float*)d_in[17];
    const float* bnw = (const float*)d_in[18];
    const float* Ww2 = (const float*)d_in[19];
    const float* bw2 = (const float*)d_in[20];

    float* ws = (float*)d_ws;
    unsigned short* q_ws = (unsigned short*)ws;                  // 5.12M bf16
    unsigned short* k_ws = (unsigned short*)(ws + 2560000);      // 5.12M bf16
    unsigned short* v_ws = (unsigned short*)(ws + 5120000);      // 5.12M bf16
    float* qw1   = ws + 7680000;
    float* kw1   = ws + 8080000;
    float* w2w1  = ws + 8480000;
    float* c1    = ws + 8484096;
    unsigned short* wp2bft = (unsigned short*)(ws + 8500000);    // 65536 bf16
    float* outp  = (float*)d_out;

    hipLaunchKernelGGL(k_prep, dim3(257), dim3(256), 0, stream,
                       Wp2, bp2, Ww1, bw1, w2w1, c1, wp2bft);
    hipLaunchKernelGGL(k_qkv, dim3(157, 1, 3), dim3(512), 0, stream,
                       feat, Wq, bq, bnq, Wk, bk, bnk, Wv, bv, q_ws, k_ws, v_ws);
    hipLaunchKernelGGL(k_qkw, dim3(1250, 2), dim3(256), 0, stream,
                       q_ws, k_ws, Ww1, qw1, kw1);
    hipLaunchKernelGGL(k_attn, dim3(1250), dim3(256), 0, stream,
                       coord, knn, Wp1, bp1, bnp, bp2, Ww2, bw2, bnw,
                       w2w1, c1, qw1, kw1, v_ws, wp2bft, outp);
}